// Round 6
// baseline (786.479 us; speedup 1.0000x reference)
//
#include <hip/hip_runtime.h>

#define BN_EPS 1e-5f
#define ELLW 48      // slot 0 = count, slots 4..47 = neighbor ids (16B-aligned), cap 44 >> max deg ~33
#define BSH 7        // bucket = dst >> 7  (128 nodes per bucket)
#define BCAP 2048    // bucket capacity (mean 1280, sd ~36 -> 21 sigma headroom)

// ---------------- detect int64 vs int32 edge_index ----------------
__global__ void k_detect(const unsigned int* __restrict__ ei, int* __restrict__ flag) {
    int t = threadIdx.x;                 // 64 threads, one wave
    unsigned int v = ei[2 * t + 1];      // odd words: int64 high-halves (==0) or real int32 values
    unsigned long long mask = __ballot(v != 0);
    if (t == 0) flag[0] = (mask == 0ULL) ? 1 : 0;   // 1 => int64
}

// ---------------- pass 1: bucket edges by dst>>BSH, pack (src<<7)|(dst&127) ----------------
__global__ __launch_bounds__(256) void k_bucket(
    const int* __restrict__ ei, const int* __restrict__ flag,
    int* __restrict__ gcnt, int* __restrict__ bdata, int E)
{
    int q = blockIdx.x * 256 + threadIdx.x;
    int e = q * 4;
    if (e >= E) return;
    bool w64 = (flag[0] != 0);
    int s[4], d[4];
    int cnt = 4;
    if (((E & 3) == 0) && (e + 4 <= E)) {
        if (w64) {
            const int4* ps = (const int4*)(ei + (size_t)2 * e);
            int4 a = ps[0], b = ps[1];
            s[0] = a.x; s[1] = a.z; s[2] = b.x; s[3] = b.z;
            const int4* pd = (const int4*)(ei + (size_t)2 * ((size_t)E + e));
            int4 c = pd[0], f = pd[1];
            d[0] = c.x; d[1] = c.z; d[2] = f.x; d[3] = f.z;
        } else {
            int4 a = *(const int4*)(ei + e);
            s[0] = a.x; s[1] = a.y; s[2] = a.z; s[3] = a.w;
            int4 c = *(const int4*)(ei + (size_t)E + e);
            d[0] = c.x; d[1] = c.y; d[2] = c.z; d[3] = c.w;
        }
    } else {
        cnt = E - e; if (cnt > 4) cnt = 4;
        for (int i = 0; i < cnt; ++i) {
            if (w64) { s[i] = ei[(size_t)2 * (e + i)]; d[i] = ei[(size_t)2 * ((size_t)E + e + i)]; }
            else     { s[i] = ei[e + i];               d[i] = ei[(size_t)E + e + i]; }
        }
        for (int i = cnt; i < 4; ++i) { s[i] = 0; d[i] = 0; }
    }
    int pos[4];
#pragma unroll
    for (int i = 0; i < 4; ++i)
        pos[i] = (i < cnt) ? atomicAdd(&gcnt[d[i] >> BSH], 1) : BCAP;
#pragma unroll
    for (int i = 0; i < 4; ++i)
        if (i < cnt && pos[i] < BCAP)
            bdata[(size_t)(d[i] >> BSH) * BCAP + pos[i]] = (s[i] << BSH) | (d[i] & 127);
}

// ---------------- pass 2: one block per bucket; LDS slot alloc; write ELL + count + dinv ----------------
__global__ __launch_bounds__(256) void k_ell(
    const int* __restrict__ gcnt, const int* __restrict__ bdata,
    int* __restrict__ ell, float* __restrict__ dinv, int N)
{
    __shared__ int lcnt[128];
    int b = blockIdx.x;
    int t = threadIdx.x;
    if (t < 128) lcnt[t] = 0;
    __syncthreads();
    int base = b << BSH;
    int cnt = min(gcnt[b], BCAP);
    const int* __restrict__ bd = bdata + (size_t)b * BCAP;
    for (int i = t; i < cnt; i += 256) {
        int v = bd[i];
        int dl = v & 127;
        int src = v >> BSH;                       // v < 2^26, arithmetic shift fine
        int pos = atomicAdd(&lcnt[dl], 1);
        if (pos < ELLW - 4)
            ell[(size_t)(base + dl) * ELLW + 4 + pos] = src;
    }
    __syncthreads();
    int n = base + t;
    if (t < 128 && n < N) {
        int c = lcnt[t];
        ell[(size_t)n * ELLW] = c;
        dinv[n] = 1.0f / sqrtf((float)(c + 1));   // +1 self-loop
    }
}

// ---------------- fused FFN (BN-folded) + GCN layer-1 dense; out stride 32 (pad zeros) ----------------
__global__ __launch_bounds__(256) void k_ffn(
    const float* __restrict__ x,
    const float* __restrict__ W1, const float* __restrict__ b1,
    const float* __restrict__ g1, const float* __restrict__ be1,
    const float* __restrict__ m1, const float* __restrict__ v1,
    const float* __restrict__ W2, const float* __restrict__ b2,
    const float* __restrict__ g2, const float* __restrict__ be2,
    const float* __restrict__ m2, const float* __restrict__ v2,
    const float* __restrict__ Wc1,
    const float* __restrict__ dinv,
    float* __restrict__ T, int N)
{
    __shared__ float sW1[25 * 100];
    __shared__ float sB1[100];
    __shared__ float sW2[100 * 25];
    __shared__ float sB2[25];
    __shared__ float sWc[25 * 25];
    int t = threadIdx.x;
    for (int idx = t; idx < 100; idx += 256) {
        float s = g1[idx] * rsqrtf(v1[idx] + BN_EPS);
        sB1[idx] = (b1[idx] - m1[idx]) * s + be1[idx];
        for (int k = 0; k < 25; ++k) sW1[k * 100 + idx] = W1[k * 100 + idx] * s;
    }
    for (int idx = t; idx < 25; idx += 256) {
        float s = g2[idx] * rsqrtf(v2[idx] + BN_EPS);
        sB2[idx] = (b2[idx] - m2[idx]) * s + be2[idx];
        for (int k = 0; k < 100; ++k) sW2[k * 25 + idx] = W2[k * 25 + idx] * s;
    }
    for (int idx = t; idx < 625; idx += 256) sWc[idx] = Wc1[idx];
    __syncthreads();

    int i = blockIdx.x * 256 + t;
    if (i >= N) return;

    float xi[25];
#pragma unroll
    for (int j = 0; j < 25; ++j) xi[j] = x[i * 25 + j];

    float h0[25];
#pragma unroll
    for (int j = 0; j < 25; ++j) h0[j] = sB2[j];

    for (int k = 0; k < 100; ++k) {
        float mm = sB1[k];
#pragma unroll
        for (int j = 0; j < 25; ++j) mm += xi[j] * sW1[j * 100 + k];
        float r = fmaxf(mm, 0.0f);
#pragma unroll
        for (int j = 0; j < 25; ++j) h0[j] += r * sW2[k * 25 + j];
    }

    float dv = dinv[i];
    float o32[32];
#pragma unroll
    for (int j = 0; j < 25; ++j) {
        float acc = 0.0f;
#pragma unroll
        for (int k = 0; k < 25; ++k) acc += h0[k] * sWc[k * 25 + j];
        o32[j] = dv * acc;
    }
#pragma unroll
    for (int j = 25; j < 32; ++j) o32[j] = 0.0f;
    float4* T4 = (float4*)(T + (size_t)i * 32);
#pragma unroll
    for (int q = 0; q < 8; ++q)
        T4[q] = make_float4(o32[4 * q], o32[4 * q + 1], o32[4 * q + 2], o32[4 * q + 3]);
}

// ---------------- fused layer: float4 gather (ELL) + finalize + dense + scale ----------------
// LPN = lanes/node, each lane owns 4 features. SI = input stride (floats, mult of 4).
template <int DI, int SI, int DO, int LPN>
__global__ __launch_bounds__(256) void k_layer(
    const int* __restrict__ ell,
    const float* __restrict__ dinv, const float* __restrict__ bias,   // bias: [DI]
    const float* __restrict__ W,                                      // [DI x DO]
    const float* __restrict__ Tin, float* __restrict__ Tout, int N)
{
    constexpr int SI4 = SI / 4;
    constexpr int DO4 = DO / 4;
    constexpr int PAD = LPN * 4;
    __shared__ float sW[DI * DO];
    __shared__ float sB[PAD];
    int t = threadIdx.x;
    for (int i = t; i < DI * DO; i += 256) sW[i] = W[i];
    for (int i = t; i < PAD; i += 256) sB[i] = (i < DI) ? bias[i] : 0.0f;
    __syncthreads();

    int g = t / LPN;
    int j = t % LPN;
    int n = blockIdx.x * (256 / LPN) + g;
    int nc = (n < N) ? n : (N - 1);
    const int* __restrict__ row = ell + (size_t)nc * ELLW;
    int dg = min(row[0], ELLW - 4);
    if (n >= N) dg = 0;
    float dv = dinv[nc];
    const float4* __restrict__ T4 = (const float4*)Tin;

    float4 a0 = T4[(size_t)nc * SI4 + j];   // self-loop term
    float4 a1 = make_float4(0.f, 0.f, 0.f, 0.f);
    float4 a2 = a1, a3 = a1;
    const int4* __restrict__ rowv = (const int4*)(row + 4);
    int k = 0;
    for (; k + 3 < dg; k += 4) {
        int4 s4 = rowv[k >> 2];
        float4 v0 = T4[(size_t)s4.x * SI4 + j];
        float4 v1 = T4[(size_t)s4.y * SI4 + j];
        float4 v2 = T4[(size_t)s4.z * SI4 + j];
        float4 v3 = T4[(size_t)s4.w * SI4 + j];
        a0.x += v0.x; a0.y += v0.y; a0.z += v0.z; a0.w += v0.w;
        a1.x += v1.x; a1.y += v1.y; a1.z += v1.z; a1.w += v1.w;
        a2.x += v2.x; a2.y += v2.y; a2.z += v2.z; a2.w += v2.w;
        a3.x += v3.x; a3.y += v3.y; a3.z += v3.z; a3.w += v3.w;
    }
    for (; k < dg; ++k) {
        float4 v = T4[(size_t)row[4 + k] * SI4 + j];
        a0.x += v.x; a0.y += v.y; a0.z += v.z; a0.w += v.w;
    }
    float ar[4];
    ar[0] = fmaxf(dv * (a0.x + a1.x + a2.x + a3.x) + sB[4 * j + 0], 0.0f);
    ar[1] = fmaxf(dv * (a0.y + a1.y + a2.y + a3.y) + sB[4 * j + 1], 0.0f);
    ar[2] = fmaxf(dv * (a0.z + a1.z + a2.z + a3.z) + sB[4 * j + 2], 0.0f);
    ar[3] = fmaxf(dv * (a0.w + a1.w + a2.w + a3.w) + sB[4 * j + 3], 0.0f);

    // dense via intra-group shuffle all-to-all (k-th activation = comp k&3 of lane base+(k>>2))
    int lane = t & 63;
    int base = lane - j;
    int jo = (j < DO4) ? j : 0;
    const float4* __restrict__ sW4 = (const float4*)sW;
    float4 o = make_float4(0.f, 0.f, 0.f, 0.f);
#pragma unroll
    for (int k2 = 0; k2 < DI; ++k2) {
        float av = __shfl(ar[k2 & 3], base + (k2 >> 2));
        float4 w = sW4[k2 * DO4 + jo];
        o.x += av * w.x; o.y += av * w.y; o.z += av * w.z; o.w += av * w.w;
    }
    if (n < N && j < DO4)
        ((float4*)Tout)[(size_t)n * DO4 + j] =
            make_float4(dv * o.x, dv * o.y, dv * o.z, dv * o.w);
}

// ---------------- final layer: float4 gather + finalize only (dim 4, 1 lane/node) ----------------
__global__ __launch_bounds__(256) void k_final(
    const int* __restrict__ ell,
    const float* __restrict__ dinv, const float* __restrict__ bias,
    const float* __restrict__ Tin, float* __restrict__ Tout, int N)
{
    int n = blockIdx.x * 256 + threadIdx.x;
    if (n >= N) return;
    const int* __restrict__ row = ell + (size_t)n * ELLW;
    int dg = min(row[0], ELLW - 4);
    float dv = dinv[n];
    const float4* __restrict__ T4 = (const float4*)Tin;

    float4 a0 = T4[n];
    float4 a1 = make_float4(0.f, 0.f, 0.f, 0.f);
    float4 a2 = a1, a3 = a1;
    const int4* __restrict__ rowv = (const int4*)(row + 4);
    int k = 0;
    for (; k + 3 < dg; k += 4) {
        int4 s4 = rowv[k >> 2];
        float4 v0 = T4[s4.x], v1 = T4[s4.y], v2 = T4[s4.z], v3 = T4[s4.w];
        a0.x += v0.x; a0.y += v0.y; a0.z += v0.z; a0.w += v0.w;
        a1.x += v1.x; a1.y += v1.y; a1.z += v1.z; a1.w += v1.w;
        a2.x += v2.x; a2.y += v2.y; a2.z += v2.z; a2.w += v2.w;
        a3.x += v3.x; a3.y += v3.y; a3.z += v3.z; a3.w += v3.w;
    }
    for (; k < dg; ++k) {
        float4 v = T4[row[4 + k]];
        a0.x += v.x; a0.y += v.y; a0.z += v.z; a0.w += v.w;
    }
    float4 b = *(const float4*)bias;
    ((float4*)Tout)[n] = make_float4(
        fmaxf(dv * (a0.x + a1.x + a2.x + a3.x) + b.x, 0.0f),
        fmaxf(dv * (a0.y + a1.y + a2.y + a3.y) + b.y, 0.0f),
        fmaxf(dv * (a0.z + a1.z + a2.z + a3.z) + b.z, 0.0f),
        fmaxf(dv * (a0.w + a1.w + a2.w + a3.w) + b.w, 0.0f));
}

// ---------------- FC: [1000,1200] @ [1200,4] + bias ----------------
__global__ __launch_bounds__(256) void k_fc(
    const float* __restrict__ H, const float* __restrict__ Wfc,
    const float* __restrict__ bfc, float* __restrict__ out)
{
    int r = blockIdx.x;          // 1000 rows
    int t = threadIdx.x;
    float p0 = 0.f, p1 = 0.f, p2 = 0.f, p3 = 0.f;
    for (int k = t; k < 1200; k += 256) {
        float h = H[(size_t)r * 1200 + k];
        p0 += h * Wfc[k * 4 + 0];
        p1 += h * Wfc[k * 4 + 1];
        p2 += h * Wfc[k * 4 + 2];
        p3 += h * Wfc[k * 4 + 3];
    }
#pragma unroll
    for (int off = 32; off > 0; off >>= 1) {
        p0 += __shfl_down(p0, off);
        p1 += __shfl_down(p1, off);
        p2 += __shfl_down(p2, off);
        p3 += __shfl_down(p3, off);
    }
    __shared__ float red[4][4];
    int w = t >> 6, lane = t & 63;
    if (lane == 0) { red[w][0] = p0; red[w][1] = p1; red[w][2] = p2; red[w][3] = p3; }
    __syncthreads();
    if (t < 4) {
        float s = red[0][t] + red[1][t] + red[2][t] + red[3][t];
        out[r * 4 + t] = s + bfc[t];
    }
}

// ---------------------------------------------------------------------------
extern "C" void kernel_launch(void* const* d_in, const int* in_sizes, int n_in,
                              void* d_out, int out_size, void* d_ws, size_t ws_size,
                              hipStream_t stream) {
    const float* x   = (const float*)d_in[0];
    const int*   ei  = (const int*)d_in[1];
    const float* W1  = (const float*)d_in[2];
    const float* b1  = (const float*)d_in[3];
    const float* g1  = (const float*)d_in[4];
    const float* be1 = (const float*)d_in[5];
    const float* m1  = (const float*)d_in[6];
    const float* v1  = (const float*)d_in[7];
    const float* W2  = (const float*)d_in[8];
    const float* b2  = (const float*)d_in[9];
    const float* g2  = (const float*)d_in[10];
    const float* be2 = (const float*)d_in[11];
    const float* m2  = (const float*)d_in[12];
    const float* v2  = (const float*)d_in[13];
    const float* Wc1 = (const float*)d_in[14];
    const float* bc1 = (const float*)d_in[15];
    const float* Wc2 = (const float*)d_in[16];
    const float* bc2 = (const float*)d_in[17];
    const float* Wc3 = (const float*)d_in[18];
    const float* bc3 = (const float*)d_in[19];
    const float* Wc4 = (const float*)d_in[20];
    const float* bc4 = (const float*)d_in[21];
    const float* Wc5 = (const float*)d_in[22];
    const float* bc5 = (const float*)d_in[23];
    const float* Wfc = (const float*)d_in[24];
    const float* bfc = (const float*)d_in[25];

    const int N = in_sizes[0] / 25;       // 300000
    const int E = in_sizes[1] / 2;        // 3000000
    const int NBUCK = (N + 127) >> BSH;   // 2344

    // ---- workspace layout (256B aligned) ----
    char* ws = (char*)d_ws;
    size_t off = 0;
    auto alloc = [&](size_t bytes) { size_t o = off; off += (bytes + 255) & ~(size_t)255; return o; };
    size_t o_flag = alloc(256);
    size_t o_gcnt = alloc((size_t)NBUCK * 4);
    size_t o_dinv = alloc((size_t)N * 4);
    size_t o_ell  = alloc((size_t)N * ELLW * 4);   // 57.6 MB
    size_t o_A = alloc((size_t)N * 32 * 4);        // stride-32 buffer (38.4 MB)
    size_t o_B = alloc((size_t)N * 16 * 4);        // stride-16 buffer (19.2 MB)
    (void)alloc(4096);                             // tail pad

    int*   flag = (int*)(ws + o_flag);
    int*   gcnt = (int*)(ws + o_gcnt);
    float* dinv = (float*)(ws + o_dinv);
    int*   ell  = (int*)(ws + o_ell);
    float* A = (float*)(ws + o_A);
    float* B_ = (float*)(ws + o_B);
    int*   bdata = (int*)A;   // 19.2 MB alias: dead before k_ffn writes A (stream-ordered)

    const int B = 256;
    int gN = (N + B - 1) / B;
    int EQ = (E + 3) / 4;
    int gQ = (EQ + B - 1) / B;

    k_detect<<<1, 64, 0, stream>>>((const unsigned int*)ei, flag);
    hipMemsetAsync(gcnt, 0, (size_t)NBUCK * 4, stream);
    k_bucket<<<gQ, B, 0, stream>>>(ei, flag, gcnt, bdata, E);
    k_ell<<<NBUCK, B, 0, stream>>>(gcnt, bdata, ell, dinv, N);

    // FFN (BN folded) + layer1 dense:  T1 = A (dim 25, stride 32)
    k_ffn<<<gN, B, 0, stream>>>(x, W1, b1, g1, be1, m1, v1, W2, b2, g2, be2, m2, v2,
                                Wc1, dinv, A, N);
    // L1: gather(25,s32) + bc1 + Wc2 -> B (dim 16)
    k_layer<25, 32, 16, 8><<<(N * 8 + B - 1) / B, B, 0, stream>>>(ell, dinv, bc1, Wc2, A, B_, N);
    // L2: gather(16) + bc2 + Wc3 -> A (dim 16)
    k_layer<16, 16, 16, 4><<<(N * 4 + B - 1) / B, B, 0, stream>>>(ell, dinv, bc2, Wc3, B_, A, N);
    // L3: gather(16) + bc3 + Wc4 -> B (dim 8)
    k_layer<16, 16, 8, 4><<<(N * 4 + B - 1) / B, B, 0, stream>>>(ell, dinv, bc3, Wc4, A, B_, N);
    // L4: gather(8) + bc4 + Wc5 -> A (dim 4)
    k_layer<8, 8, 4, 2><<<(N * 2 + B - 1) / B, B, 0, stream>>>(ell, dinv, bc4, Wc5, B_, A, N);
    // L5: gather(4) + bc5 + relu -> B (dim 4, final node features)
    k_final<<<gN, B, 0, stream>>>(ell, dinv, bc5, A, B_, N);
    // FC
    k_fc<<<1000, B, 0, stream>>>(B_, Wfc, bfc, (float*)d_out);
}

// Round 7
// 539.120 us; speedup vs baseline: 1.4588x; 1.4588x over previous
//
#include <hip/hip_runtime.h>

#define BN_EPS 1e-5f
#define ELLW 48      // slot 0 = count, slots 4..47 = neighbor ids (16B-aligned), cap 44 >> max deg ~33
#define BSH2 11      // bucket = dst >> 11  (2048 nodes per bucket)
#define NPB 2048
#define MAXBK 160    // compile-time bound on bucket count (N <= 327680)
#define BCAP2 26624  // per-bucket edge capacity (mean ~20.4K, +43 sigma)

// ---------------- detect int64 vs int32 edge_index ----------------
__global__ void k_detect(const unsigned int* __restrict__ ei, int* __restrict__ flag) {
    int t = threadIdx.x;                 // 64 threads, one wave
    unsigned int v = ei[2 * t + 1];      // odd words: int64 high-halves (==0) or real int32 values
    unsigned long long mask = __ballot(v != 0);
    if (t == 0) flag[0] = (mask == 0ULL) ? 1 : 0;   // 1 => int64
}

// ---------------- pass 1: block-grouped partition by dst>>11 ----------------
__global__ __launch_bounds__(256) void k_part(
    const int* __restrict__ ei, const int* __restrict__ flag,
    int* __restrict__ gcnt, int* __restrict__ bdata, int E)
{
    __shared__ int hist[MAXBK];
    __shared__ int cur[MAXBK];
    __shared__ int gbase[MAXBK];
    __shared__ int locstart[MAXBK + 1];
    __shared__ int sc[256];
    __shared__ int stage[1024];

    int t = threadIdx.x;
    int blockBase = blockIdx.x * 1024;
    int blockCnt = E - blockBase; if (blockCnt > 1024) blockCnt = 1024; if (blockCnt < 0) blockCnt = 0;

    for (int i = t; i < MAXBK; i += 256) hist[i] = 0;
    __syncthreads();

    bool w64 = (flag[0] != 0);
    int e = blockBase + t * 4;
    int s[4], d[4];
    int cnt = 0;
    if (e < E) {
        cnt = E - e; if (cnt > 4) cnt = 4;
        if (cnt == 4) {
            if (w64) {
                const int4* ps = (const int4*)(ei + (size_t)2 * e);
                int4 a = ps[0], b = ps[1];
                s[0] = a.x; s[1] = a.z; s[2] = b.x; s[3] = b.z;
                const int4* pd = (const int4*)(ei + (size_t)2 * ((size_t)E + e));
                int4 c = pd[0], f = pd[1];
                d[0] = c.x; d[1] = c.z; d[2] = f.x; d[3] = f.z;
            } else {
                int4 a = *(const int4*)(ei + e);
                s[0] = a.x; s[1] = a.y; s[2] = a.z; s[3] = a.w;
                int4 c = *(const int4*)(ei + (size_t)E + e);
                d[0] = c.x; d[1] = c.y; d[2] = c.z; d[3] = c.w;
            }
        } else {
            for (int i = 0; i < cnt; ++i) {
                if (w64) { s[i] = ei[(size_t)2 * (e + i)]; d[i] = ei[(size_t)2 * ((size_t)E + e + i)]; }
                else     { s[i] = ei[e + i];               d[i] = ei[(size_t)E + e + i]; }
            }
        }
    }
    int bk[4], pk[4];
    for (int i = 0; i < cnt; ++i) {
        bk[i] = d[i] >> BSH2;
        pk[i] = (s[i] << BSH2) | (d[i] & (NPB - 1));
        atomicAdd(&hist[bk[i]], 1);
    }
    __syncthreads();

    // inclusive scan over MAXBK (padded to 256)
    sc[t] = (t < MAXBK) ? hist[t] : 0;
    __syncthreads();
    for (int off = 1; off < 256; off <<= 1) {
        int x = (t >= off) ? sc[t - off] : 0;
        __syncthreads();
        sc[t] += x;
        __syncthreads();
    }
    if (t < MAXBK) {
        locstart[t] = sc[t] - hist[t];
        cur[t] = sc[t] - hist[t];
        if (hist[t] > 0) gbase[t] = atomicAdd(&gcnt[t], hist[t]);
    }
    if (t == 255) locstart[MAXBK] = sc[MAXBK - 1];
    __syncthreads();

    // stage grouped by bucket
    for (int i = 0; i < cnt; ++i) {
        int p = atomicAdd(&cur[bk[i]], 1);
        stage[p] = pk[i];
    }
    __syncthreads();

    // copy groups out contiguously
    for (int sIdx = t; sIdx < blockCnt; sIdx += 256) {
        int lo = 0, hi = MAXBK;
        while (hi - lo > 1) {
            int mid = (lo + hi) >> 1;
            if (locstart[mid] <= sIdx) lo = mid; else hi = mid;
        }
        int g = gbase[lo] + (sIdx - locstart[lo]);
        if (g < BCAP2) bdata[(size_t)lo * BCAP2 + g] = stage[sIdx];
    }
}

// ---------------- pass 2: one block per bucket; LDS slot alloc; write ELL + count + dinv ----------------
__global__ __launch_bounds__(256) void k_ell2(
    const int* __restrict__ gcnt, const int* __restrict__ bdata,
    int* __restrict__ ell, float* __restrict__ dinv, int N)
{
    __shared__ int lcnt[NPB];
    int b = blockIdx.x;
    int t = threadIdx.x;
    for (int i = t; i < NPB; i += 256) lcnt[i] = 0;
    __syncthreads();
    int base = b << BSH2;
    int cnt = min(gcnt[b], BCAP2);
    const int* __restrict__ bd = bdata + (size_t)b * BCAP2;
    for (int i = t; i < cnt; i += 256) {
        int v = bd[i];
        int dl = v & (NPB - 1);
        int src = v >> BSH2;                      // v < 2^30, arithmetic shift fine
        int pos = atomicAdd(&lcnt[dl], 1);
        if (pos < ELLW - 4)
            ell[(size_t)(base + dl) * ELLW + 4 + pos] = src;
    }
    __syncthreads();
    for (int i = t; i < NPB; i += 256) {
        int n = base + i;
        if (n < N) {
            int c = lcnt[i];
            ell[(size_t)n * ELLW] = c;
            dinv[n] = 1.0f / sqrtf((float)(c + 1));   // +1 self-loop
        }
    }
}

// ---------------- fused FFN (BN-folded) + GCN layer-1 dense; out stride 32 (pad zeros) ----------------
__global__ __launch_bounds__(256) void k_ffn(
    const float* __restrict__ x,
    const float* __restrict__ W1, const float* __restrict__ b1,
    const float* __restrict__ g1, const float* __restrict__ be1,
    const float* __restrict__ m1, const float* __restrict__ v1,
    const float* __restrict__ W2, const float* __restrict__ b2,
    const float* __restrict__ g2, const float* __restrict__ be2,
    const float* __restrict__ m2, const float* __restrict__ v2,
    const float* __restrict__ Wc1,
    const float* __restrict__ dinv,
    float* __restrict__ T, int N)
{
    __shared__ float sW1[25 * 100];
    __shared__ float sB1[100];
    __shared__ float sW2[100 * 25];
    __shared__ float sB2[25];
    __shared__ float sWc[25 * 25];
    int t = threadIdx.x;
    for (int idx = t; idx < 100; idx += 256) {
        float s = g1[idx] * rsqrtf(v1[idx] + BN_EPS);
        sB1[idx] = (b1[idx] - m1[idx]) * s + be1[idx];
        for (int k = 0; k < 25; ++k) sW1[k * 100 + idx] = W1[k * 100 + idx] * s;
    }
    for (int idx = t; idx < 25; idx += 256) {
        float s = g2[idx] * rsqrtf(v2[idx] + BN_EPS);
        sB2[idx] = (b2[idx] - m2[idx]) * s + be2[idx];
        for (int k = 0; k < 100; ++k) sW2[k * 25 + idx] = W2[k * 25 + idx] * s;
    }
    for (int idx = t; idx < 625; idx += 256) sWc[idx] = Wc1[idx];
    __syncthreads();

    int i = blockIdx.x * 256 + t;
    if (i >= N) return;

    float xi[25];
#pragma unroll
    for (int j = 0; j < 25; ++j) xi[j] = x[i * 25 + j];

    float h0[25];
#pragma unroll
    for (int j = 0; j < 25; ++j) h0[j] = sB2[j];

    for (int k = 0; k < 100; ++k) {
        float mm = sB1[k];
#pragma unroll
        for (int j = 0; j < 25; ++j) mm += xi[j] * sW1[j * 100 + k];
        float r = fmaxf(mm, 0.0f);
#pragma unroll
        for (int j = 0; j < 25; ++j) h0[j] += r * sW2[k * 25 + j];
    }

    float dv = dinv[i];
    float o32[32];
#pragma unroll
    for (int j = 0; j < 25; ++j) {
        float acc = 0.0f;
#pragma unroll
        for (int k = 0; k < 25; ++k) acc += h0[k] * sWc[k * 25 + j];
        o32[j] = dv * acc;
    }
#pragma unroll
    for (int j = 25; j < 32; ++j) o32[j] = 0.0f;
    float4* T4 = (float4*)(T + (size_t)i * 32);
#pragma unroll
    for (int q = 0; q < 8; ++q)
        T4[q] = make_float4(o32[4 * q], o32[4 * q + 1], o32[4 * q + 2], o32[4 * q + 3]);
}

// ---------------- fused layer: float4 gather (ELL) + finalize + dense + scale ----------------
// LPN = lanes/node, each lane owns 4 features. SI = input stride (floats, mult of 4).
template <int DI, int SI, int DO, int LPN>
__global__ __launch_bounds__(256) void k_layer(
    const int* __restrict__ ell,
    const float* __restrict__ dinv, const float* __restrict__ bias,   // bias: [DI]
    const float* __restrict__ W,                                      // [DI x DO]
    const float* __restrict__ Tin, float* __restrict__ Tout, int N)
{
    constexpr int SI4 = SI / 4;
    constexpr int DO4 = DO / 4;
    constexpr int PAD = LPN * 4;
    __shared__ float sW[DI * DO];
    __shared__ float sB[PAD];
    int t = threadIdx.x;
    for (int i = t; i < DI * DO; i += 256) sW[i] = W[i];
    for (int i = t; i < PAD; i += 256) sB[i] = (i < DI) ? bias[i] : 0.0f;
    __syncthreads();

    int g = t / LPN;
    int j = t % LPN;
    int n = blockIdx.x * (256 / LPN) + g;
    int nc = (n < N) ? n : (N - 1);
    const int* __restrict__ row = ell + (size_t)nc * ELLW;
    int dg = min(row[0], ELLW - 4);
    if (n >= N) dg = 0;
    float dv = dinv[nc];
    const float4* __restrict__ T4 = (const float4*)Tin;

    float4 a0 = T4[(size_t)nc * SI4 + j];   // self-loop term
    float4 a1 = make_float4(0.f, 0.f, 0.f, 0.f);
    float4 a2 = a1, a3 = a1;
    const int4* __restrict__ rowv = (const int4*)(row + 4);
    int k = 0;
    for (; k + 3 < dg; k += 4) {
        int4 s4 = rowv[k >> 2];
        float4 v0 = T4[(size_t)s4.x * SI4 + j];
        float4 v1 = T4[(size_t)s4.y * SI4 + j];
        float4 v2 = T4[(size_t)s4.z * SI4 + j];
        float4 v3 = T4[(size_t)s4.w * SI4 + j];
        a0.x += v0.x; a0.y += v0.y; a0.z += v0.z; a0.w += v0.w;
        a1.x += v1.x; a1.y += v1.y; a1.z += v1.z; a1.w += v1.w;
        a2.x += v2.x; a2.y += v2.y; a2.z += v2.z; a2.w += v2.w;
        a3.x += v3.x; a3.y += v3.y; a3.z += v3.z; a3.w += v3.w;
    }
    for (; k < dg; ++k) {
        float4 v = T4[(size_t)row[4 + k] * SI4 + j];
        a0.x += v.x; a0.y += v.y; a0.z += v.z; a0.w += v.w;
    }
    float ar[4];
    ar[0] = fmaxf(dv * (a0.x + a1.x + a2.x + a3.x) + sB[4 * j + 0], 0.0f);
    ar[1] = fmaxf(dv * (a0.y + a1.y + a2.y + a3.y) + sB[4 * j + 1], 0.0f);
    ar[2] = fmaxf(dv * (a0.z + a1.z + a2.z + a3.z) + sB[4 * j + 2], 0.0f);
    ar[3] = fmaxf(dv * (a0.w + a1.w + a2.w + a3.w) + sB[4 * j + 3], 0.0f);

    // dense via intra-group shuffle all-to-all (k-th activation = comp k&3 of lane base+(k>>2))
    int lane = t & 63;
    int base = lane - j;
    int jo = (j < DO4) ? j : 0;
    const float4* __restrict__ sW4 = (const float4*)sW;
    float4 o = make_float4(0.f, 0.f, 0.f, 0.f);
#pragma unroll
    for (int k2 = 0; k2 < DI; ++k2) {
        float av = __shfl(ar[k2 & 3], base + (k2 >> 2));
        float4 w = sW4[k2 * DO4 + jo];
        o.x += av * w.x; o.y += av * w.y; o.z += av * w.z; o.w += av * w.w;
    }
    if (n < N && j < DO4)
        ((float4*)Tout)[(size_t)n * DO4 + j] =
            make_float4(dv * o.x, dv * o.y, dv * o.z, dv * o.w);
}

// ---------------- final layer: float4 gather + finalize only (dim 4, 1 lane/node) ----------------
__global__ __launch_bounds__(256) void k_final(
    const int* __restrict__ ell,
    const float* __restrict__ dinv, const float* __restrict__ bias,
    const float* __restrict__ Tin, float* __restrict__ Tout, int N)
{
    int n = blockIdx.x * 256 + threadIdx.x;
    if (n >= N) return;
    const int* __restrict__ row = ell + (size_t)n * ELLW;
    int dg = min(row[0], ELLW - 4);
    float dv = dinv[n];
    const float4* __restrict__ T4 = (const float4*)Tin;

    float4 a0 = T4[n];
    float4 a1 = make_float4(0.f, 0.f, 0.f, 0.f);
    float4 a2 = a1, a3 = a1;
    const int4* __restrict__ rowv = (const int4*)(row + 4);
    int k = 0;
    for (; k + 3 < dg; k += 4) {
        int4 s4 = rowv[k >> 2];
        float4 v0 = T4[s4.x], v1 = T4[s4.y], v2 = T4[s4.z], v3 = T4[s4.w];
        a0.x += v0.x; a0.y += v0.y; a0.z += v0.z; a0.w += v0.w;
        a1.x += v1.x; a1.y += v1.y; a1.z += v1.z; a1.w += v1.w;
        a2.x += v2.x; a2.y += v2.y; a2.z += v2.z; a2.w += v2.w;
        a3.x += v3.x; a3.y += v3.y; a3.z += v3.z; a3.w += v3.w;
    }
    for (; k < dg; ++k) {
        float4 v = T4[row[4 + k]];
        a0.x += v.x; a0.y += v.y; a0.z += v.z; a0.w += v.w;
    }
    float4 b = *(const float4*)bias;
    ((float4*)Tout)[n] = make_float4(
        fmaxf(dv * (a0.x + a1.x + a2.x + a3.x) + b.x, 0.0f),
        fmaxf(dv * (a0.y + a1.y + a2.y + a3.y) + b.y, 0.0f),
        fmaxf(dv * (a0.z + a1.z + a2.z + a3.z) + b.z, 0.0f),
        fmaxf(dv * (a0.w + a1.w + a2.w + a3.w) + b.w, 0.0f));
}

// ---------------- FC: [1000,1200] @ [1200,4] + bias ----------------
__global__ __launch_bounds__(256) void k_fc(
    const float* __restrict__ H, const float* __restrict__ Wfc,
    const float* __restrict__ bfc, float* __restrict__ out)
{
    int r = blockIdx.x;          // 1000 rows
    int t = threadIdx.x;
    float p0 = 0.f, p1 = 0.f, p2 = 0.f, p3 = 0.f;
    for (int k = t; k < 1200; k += 256) {
        float h = H[(size_t)r * 1200 + k];
        p0 += h * Wfc[k * 4 + 0];
        p1 += h * Wfc[k * 4 + 1];
        p2 += h * Wfc[k * 4 + 2];
        p3 += h * Wfc[k * 4 + 3];
    }
#pragma unroll
    for (int off = 32; off > 0; off >>= 1) {
        p0 += __shfl_down(p0, off);
        p1 += __shfl_down(p1, off);
        p2 += __shfl_down(p2, off);
        p3 += __shfl_down(p3, off);
    }
    __shared__ float red[4][4];
    int w = t >> 6, lane = t & 63;
    if (lane == 0) { red[w][0] = p0; red[w][1] = p1; red[w][2] = p2; red[w][3] = p3; }
    __syncthreads();
    if (t < 4) {
        float s = red[0][t] + red[1][t] + red[2][t] + red[3][t];
        out[r * 4 + t] = s + bfc[t];
    }
}

// ---------------------------------------------------------------------------
extern "C" void kernel_launch(void* const* d_in, const int* in_sizes, int n_in,
                              void* d_out, int out_size, void* d_ws, size_t ws_size,
                              hipStream_t stream) {
    const float* x   = (const float*)d_in[0];
    const int*   ei  = (const int*)d_in[1];
    const float* W1  = (const float*)d_in[2];
    const float* b1  = (const float*)d_in[3];
    const float* g1  = (const float*)d_in[4];
    const float* be1 = (const float*)d_in[5];
    const float* m1  = (const float*)d_in[6];
    const float* v1  = (const float*)d_in[7];
    const float* W2  = (const float*)d_in[8];
    const float* b2  = (const float*)d_in[9];
    const float* g2  = (const float*)d_in[10];
    const float* be2 = (const float*)d_in[11];
    const float* m2  = (const float*)d_in[12];
    const float* v2  = (const float*)d_in[13];
    const float* Wc1 = (const float*)d_in[14];
    const float* bc1 = (const float*)d_in[15];
    const float* Wc2 = (const float*)d_in[16];
    const float* bc2 = (const float*)d_in[17];
    const float* Wc3 = (const float*)d_in[18];
    const float* bc3 = (const float*)d_in[19];
    const float* Wc4 = (const float*)d_in[20];
    const float* bc4 = (const float*)d_in[21];
    const float* Wc5 = (const float*)d_in[22];
    const float* bc5 = (const float*)d_in[23];
    const float* Wfc = (const float*)d_in[24];
    const float* bfc = (const float*)d_in[25];

    const int N = in_sizes[0] / 25;          // 300000
    const int E = in_sizes[1] / 2;           // 3000000
    const int NBUCK = (N + NPB - 1) >> BSH2; // 147

    // ---- workspace layout (256B aligned) ----
    char* ws = (char*)d_ws;
    size_t off = 0;
    auto alloc = [&](size_t bytes) { size_t o = off; off += (bytes + 255) & ~(size_t)255; return o; };
    size_t o_flag = alloc(256);
    size_t o_gcnt = alloc((size_t)MAXBK * 4);
    size_t o_dinv = alloc((size_t)N * 4);
    size_t o_ell  = alloc((size_t)N * ELLW * 4);   // 57.6 MB
    size_t o_A = alloc((size_t)N * 32 * 4);        // stride-32 buffer (38.4 MB)
    size_t o_B = alloc((size_t)N * 16 * 4);        // stride-16 buffer (19.2 MB)
    (void)alloc(4096);                             // tail pad

    int*   flag = (int*)(ws + o_flag);
    int*   gcnt = (int*)(ws + o_gcnt);
    float* dinv = (float*)(ws + o_dinv);
    int*   ell  = (int*)(ws + o_ell);
    float* A = (float*)(ws + o_A);
    float* B_ = (float*)(ws + o_B);
    int*   bdata = (int*)A;   // 15.7 MB alias: dead before k_ffn writes A (stream-ordered)

    const int B = 256;
    int gN = (N + B - 1) / B;
    int gP = (E + 1023) / 1024;

    k_detect<<<1, 64, 0, stream>>>((const unsigned int*)ei, flag);
    hipMemsetAsync(gcnt, 0, (size_t)MAXBK * 4, stream);
    k_part<<<gP, B, 0, stream>>>(ei, flag, gcnt, bdata, E);
    k_ell2<<<NBUCK, B, 0, stream>>>(gcnt, bdata, ell, dinv, N);

    // FFN (BN folded) + layer1 dense:  T1 = A (dim 25, stride 32)
    k_ffn<<<gN, B, 0, stream>>>(x, W1, b1, g1, be1, m1, v1, W2, b2, g2, be2, m2, v2,
                                Wc1, dinv, A, N);
    // L1: gather(25,s32) + bc1 + Wc2 -> B (dim 16)
    k_layer<25, 32, 16, 8><<<(N * 8 + B - 1) / B, B, 0, stream>>>(ell, dinv, bc1, Wc2, A, B_, N);
    // L2: gather(16) + bc2 + Wc3 -> A (dim 16)
    k_layer<16, 16, 16, 4><<<(N * 4 + B - 1) / B, B, 0, stream>>>(ell, dinv, bc2, Wc3, B_, A, N);
    // L3: gather(16) + bc3 + Wc4 -> B (dim 8)
    k_layer<16, 16, 8, 4><<<(N * 4 + B - 1) / B, B, 0, stream>>>(ell, dinv, bc3, Wc4, A, B_, N);
    // L4: gather(8) + bc4 + Wc5 -> A (dim 4)
    k_layer<8, 8, 4, 2><<<(N * 2 + B - 1) / B, B, 0, stream>>>(ell, dinv, bc4, Wc5, B_, A, N);
    // L5: gather(4) + bc5 + relu -> B (dim 4, final node features)
    k_final<<<gN, B, 0, stream>>>(ell, dinv, bc5, A, B_, N);
    // FC
    k_fc<<<1000, B, 0, stream>>>(B_, Wfc, bfc, (float*)d_out);
}

// Round 8
// 522.229 us; speedup vs baseline: 1.5060x; 1.0323x over previous
//
#include <hip/hip_runtime.h>

#define BN_EPS 1e-5f
#define ELLW 48      // slot 0 = count, slots 4..47 = neighbor ids (16B-aligned), cap 44 >> max deg ~33
#define BSH2 11      // bucket = dst >> 11  (2048 nodes per bucket)
#define NPB 2048
#define MAXBK 160    // compile-time bound on bucket count (N <= 327680)
#define BCAP2 26624  // per-bucket edge capacity (mean ~20.4K, +43 sigma)

// ---------------- detect int64 vs int32 edge_index ----------------
__global__ void k_detect(const unsigned int* __restrict__ ei, int* __restrict__ flag) {
    int t = threadIdx.x;                 // 64 threads, one wave
    unsigned int v = ei[2 * t + 1];      // odd words: int64 high-halves (==0) or real int32 values
    unsigned long long mask = __ballot(v != 0);
    if (t == 0) flag[0] = (mask == 0ULL) ? 1 : 0;   // 1 => int64
}

// ---------------- pass 1: block-grouped partition by dst>>11 ----------------
__global__ __launch_bounds__(256) void k_part(
    const int* __restrict__ ei, const int* __restrict__ flag,
    int* __restrict__ gcnt, int* __restrict__ bdata, int E)
{
    __shared__ int hist[MAXBK];
    __shared__ int cur[MAXBK];
    __shared__ int gbase[MAXBK];
    __shared__ int locstart[MAXBK + 1];
    __shared__ int sc[256];
    __shared__ int stage[1024];

    int t = threadIdx.x;
    int blockBase = blockIdx.x * 1024;
    int blockCnt = E - blockBase; if (blockCnt > 1024) blockCnt = 1024; if (blockCnt < 0) blockCnt = 0;

    for (int i = t; i < MAXBK; i += 256) hist[i] = 0;
    __syncthreads();

    bool w64 = (flag[0] != 0);
    int e = blockBase + t * 4;
    int s[4], d[4];
    int cnt = 0;
    if (e < E) {
        cnt = E - e; if (cnt > 4) cnt = 4;
        if (cnt == 4) {
            if (w64) {
                const int4* ps = (const int4*)(ei + (size_t)2 * e);
                int4 a = ps[0], b = ps[1];
                s[0] = a.x; s[1] = a.z; s[2] = b.x; s[3] = b.z;
                const int4* pd = (const int4*)(ei + (size_t)2 * ((size_t)E + e));
                int4 c = pd[0], f = pd[1];
                d[0] = c.x; d[1] = c.z; d[2] = f.x; d[3] = f.z;
            } else {
                int4 a = *(const int4*)(ei + e);
                s[0] = a.x; s[1] = a.y; s[2] = a.z; s[3] = a.w;
                int4 c = *(const int4*)(ei + (size_t)E + e);
                d[0] = c.x; d[1] = c.y; d[2] = c.z; d[3] = c.w;
            }
        } else {
            for (int i = 0; i < cnt; ++i) {
                if (w64) { s[i] = ei[(size_t)2 * (e + i)]; d[i] = ei[(size_t)2 * ((size_t)E + e + i)]; }
                else     { s[i] = ei[e + i];               d[i] = ei[(size_t)E + e + i]; }
            }
        }
    }
    int bk[4], pk[4];
    for (int i = 0; i < cnt; ++i) {
        bk[i] = d[i] >> BSH2;
        pk[i] = (s[i] << BSH2) | (d[i] & (NPB - 1));
        atomicAdd(&hist[bk[i]], 1);
    }
    __syncthreads();

    // inclusive scan over MAXBK (padded to 256)
    sc[t] = (t < MAXBK) ? hist[t] : 0;
    __syncthreads();
    for (int off = 1; off < 256; off <<= 1) {
        int x = (t >= off) ? sc[t - off] : 0;
        __syncthreads();
        sc[t] += x;
        __syncthreads();
    }
    if (t < MAXBK) {
        locstart[t] = sc[t] - hist[t];
        cur[t] = sc[t] - hist[t];
        if (hist[t] > 0) gbase[t] = atomicAdd(&gcnt[t], hist[t]);
    }
    if (t == 255) locstart[MAXBK] = sc[MAXBK - 1];
    __syncthreads();

    // stage grouped by bucket
    for (int i = 0; i < cnt; ++i) {
        int p = atomicAdd(&cur[bk[i]], 1);
        stage[p] = pk[i];
    }
    __syncthreads();

    // copy groups out contiguously
    for (int sIdx = t; sIdx < blockCnt; sIdx += 256) {
        int lo = 0, hi = MAXBK;
        while (hi - lo > 1) {
            int mid = (lo + hi) >> 1;
            if (locstart[mid] <= sIdx) lo = mid; else hi = mid;
        }
        int g = gbase[lo] + (sIdx - locstart[lo]);
        if (g < BCAP2) bdata[(size_t)lo * BCAP2 + g] = stage[sIdx];
    }
}

// ---------------- pass 2: one block per bucket; LDS slot alloc; write ELL + count + dinv ----------------
__global__ __launch_bounds__(256) void k_ell2(
    const int* __restrict__ gcnt, const int* __restrict__ bdata,
    int* __restrict__ ell, float* __restrict__ dinv, int N)
{
    __shared__ int lcnt[NPB];
    int b = blockIdx.x;
    int t = threadIdx.x;
    for (int i = t; i < NPB; i += 256) lcnt[i] = 0;
    __syncthreads();
    int base = b << BSH2;
    int cnt = min(gcnt[b], BCAP2);
    const int* __restrict__ bd = bdata + (size_t)b * BCAP2;
    for (int i = t; i < cnt; i += 256) {
        int v = bd[i];
        int dl = v & (NPB - 1);
        int src = v >> BSH2;                      // v < 2^30, arithmetic shift fine
        int pos = atomicAdd(&lcnt[dl], 1);
        if (pos < ELLW - 4)
            ell[(size_t)(base + dl) * ELLW + 4 + pos] = src;
    }
    __syncthreads();
    for (int i = t; i < NPB; i += 256) {
        int n = base + i;
        if (n < N) {
            int c = lcnt[i];
            ell[(size_t)n * ELLW] = c;
            dinv[n] = 1.0f / sqrtf((float)(c + 1));   // +1 self-loop
        }
    }
}

// ---------------- fused FFN (BN-folded) + GCN layer-1 dense; out stride 32 (pad zeros) ----------------
// Chunked: 4 chunks of 25 hidden units; 25 independent FMA chains at every stage;
// all LDS weight rows padded to 28 floats (112B = 7x16B) for aligned ds_read_b128.
__global__ __launch_bounds__(256) void k_ffn(
    const float* __restrict__ x,
    const float* __restrict__ W1, const float* __restrict__ b1,
    const float* __restrict__ g1, const float* __restrict__ be1,
    const float* __restrict__ m1, const float* __restrict__ v1,
    const float* __restrict__ W2, const float* __restrict__ b2,
    const float* __restrict__ g2, const float* __restrict__ be2,
    const float* __restrict__ m2, const float* __restrict__ v2,
    const float* __restrict__ Wc1,
    const float* __restrict__ dinv,
    float* __restrict__ T, int N)
{
    __shared__ float sW1c[4 * 25 * 28];   // [kc][j][k'] padded
    __shared__ float sW2p[100 * 28];      // [k][j2]     padded
    __shared__ float sWcp[25 * 28];       // [k][j]      padded
    __shared__ float sB1[100], sS1[100];
    __shared__ float sB2[32], sS2[32];
    int t = threadIdx.x;
    if (t < 100) {
        float s = g1[t] * rsqrtf(v1[t] + BN_EPS);
        sS1[t] = s;
        sB1[t] = (b1[t] - m1[t]) * s + be1[t];
    }
    if (t >= 128 && t < 153) {
        int u = t - 128;
        float s = g2[u] * rsqrtf(v2[u] + BN_EPS);
        sS2[u] = s;
        sB2[u] = (b2[u] - m2[u]) * s + be2[u];
    }
    __syncthreads();
    for (int q = t; q < 2500; q += 256) {
        int j = q / 100, k = q % 100;
        int kc = k / 25, kk = k % 25;
        sW1c[(kc * 25 + j) * 28 + kk] = W1[q] * sS1[k];
    }
    for (int q = t; q < 2500; q += 256) {
        int k = q / 25, j2 = q % 25;
        sW2p[k * 28 + j2] = W2[q] * sS2[j2];
    }
    for (int q = t; q < 625; q += 256) {
        int k = q / 25, j = q % 25;
        sWcp[k * 28 + j] = Wc1[q];
    }
    __syncthreads();

    int i = blockIdx.x * 256 + t;
    if (i >= N) return;

    float xi[25];
#pragma unroll
    for (int j = 0; j < 25; ++j) xi[j] = x[(size_t)i * 25 + j];

    float h0[25];
#pragma unroll
    for (int j = 0; j < 25; ++j) h0[j] = sB2[j];

#pragma unroll 1
    for (int kc = 0; kc < 4; ++kc) {
        float hm[25];
#pragma unroll
        for (int kk = 0; kk < 25; ++kk) hm[kk] = sB1[kc * 25 + kk];
#pragma unroll
        for (int j = 0; j < 25; ++j) {
            float xv = xi[j];
            const float* __restrict__ wr = &sW1c[(kc * 25 + j) * 28];
#pragma unroll
            for (int kk = 0; kk < 25; ++kk) hm[kk] += xv * wr[kk];
        }
#pragma unroll
        for (int kk = 0; kk < 25; ++kk) {
            float r = fmaxf(hm[kk], 0.0f);
            const float* __restrict__ w2r = &sW2p[(kc * 25 + kk) * 28];
#pragma unroll
            for (int j2 = 0; j2 < 25; ++j2) h0[j2] += r * w2r[j2];
        }
    }

    float dv = dinv[i];
    float o32[32];
#pragma unroll
    for (int j = 0; j < 25; ++j) o32[j] = 0.0f;
#pragma unroll
    for (int k = 0; k < 25; ++k) {
        float hv = h0[k];
        const float* __restrict__ wr = &sWcp[k * 28];
#pragma unroll
        for (int j = 0; j < 25; ++j) o32[j] += hv * wr[j];
    }
#pragma unroll
    for (int j = 0; j < 25; ++j) o32[j] *= dv;
#pragma unroll
    for (int j = 25; j < 32; ++j) o32[j] = 0.0f;
    float4* T4 = (float4*)(T + (size_t)i * 32);
#pragma unroll
    for (int q = 0; q < 8; ++q)
        T4[q] = make_float4(o32[4 * q], o32[4 * q + 1], o32[4 * q + 2], o32[4 * q + 3]);
}

// ---------------- fused layer: float4 gather (ELL) + finalize + dense + scale ----------------
// LPN = lanes/node, each lane owns 4 features. SI = input stride (floats, mult of 4).
template <int DI, int SI, int DO, int LPN>
__global__ __launch_bounds__(256) void k_layer(
    const int* __restrict__ ell,
    const float* __restrict__ dinv, const float* __restrict__ bias,   // bias: [DI]
    const float* __restrict__ W,                                      // [DI x DO]
    const float* __restrict__ Tin, float* __restrict__ Tout, int N)
{
    constexpr int SI4 = SI / 4;
    constexpr int DO4 = DO / 4;
    constexpr int PAD = LPN * 4;
    __shared__ float sW[DI * DO];
    __shared__ float sB[PAD];
    int t = threadIdx.x;
    for (int i = t; i < DI * DO; i += 256) sW[i] = W[i];
    for (int i = t; i < PAD; i += 256) sB[i] = (i < DI) ? bias[i] : 0.0f;
    __syncthreads();

    int g = t / LPN;
    int j = t % LPN;
    int n = blockIdx.x * (256 / LPN) + g;
    int nc = (n < N) ? n : (N - 1);
    const int* __restrict__ row = ell + (size_t)nc * ELLW;
    int dg = min(row[0], ELLW - 4);
    if (n >= N) dg = 0;
    float dv = dinv[nc];
    const float4* __restrict__ T4 = (const float4*)Tin;

    float4 a0 = T4[(size_t)nc * SI4 + j];   // self-loop term
    float4 a1 = make_float4(0.f, 0.f, 0.f, 0.f);
    float4 a2 = a1, a3 = a1;
    const int4* __restrict__ rowv = (const int4*)(row + 4);
    int k = 0;
    for (; k + 3 < dg; k += 4) {
        int4 s4 = rowv[k >> 2];
        float4 v0 = T4[(size_t)s4.x * SI4 + j];
        float4 v1 = T4[(size_t)s4.y * SI4 + j];
        float4 v2 = T4[(size_t)s4.z * SI4 + j];
        float4 v3 = T4[(size_t)s4.w * SI4 + j];
        a0.x += v0.x; a0.y += v0.y; a0.z += v0.z; a0.w += v0.w;
        a1.x += v1.x; a1.y += v1.y; a1.z += v1.z; a1.w += v1.w;
        a2.x += v2.x; a2.y += v2.y; a2.z += v2.z; a2.w += v2.w;
        a3.x += v3.x; a3.y += v3.y; a3.z += v3.z; a3.w += v3.w;
    }
    for (; k < dg; ++k) {
        float4 v = T4[(size_t)row[4 + k] * SI4 + j];
        a0.x += v.x; a0.y += v.y; a0.z += v.z; a0.w += v.w;
    }
    float ar[4];
    ar[0] = fmaxf(dv * (a0.x + a1.x + a2.x + a3.x) + sB[4 * j + 0], 0.0f);
    ar[1] = fmaxf(dv * (a0.y + a1.y + a2.y + a3.y) + sB[4 * j + 1], 0.0f);
    ar[2] = fmaxf(dv * (a0.z + a1.z + a2.z + a3.z) + sB[4 * j + 2], 0.0f);
    ar[3] = fmaxf(dv * (a0.w + a1.w + a2.w + a3.w) + sB[4 * j + 3], 0.0f);

    // dense via intra-group shuffle all-to-all (k-th activation = comp k&3 of lane base+(k>>2))
    int lane = t & 63;
    int base = lane - j;
    int jo = (j < DO4) ? j : 0;
    const float4* __restrict__ sW4 = (const float4*)sW;
    float4 o = make_float4(0.f, 0.f, 0.f, 0.f);
#pragma unroll
    for (int k2 = 0; k2 < DI; ++k2) {
        float av = __shfl(ar[k2 & 3], base + (k2 >> 2));
        float4 w = sW4[k2 * DO4 + jo];
        o.x += av * w.x; o.y += av * w.y; o.z += av * w.z; o.w += av * w.w;
    }
    if (n < N && j < DO4)
        ((float4*)Tout)[(size_t)n * DO4 + j] =
            make_float4(dv * o.x, dv * o.y, dv * o.z, dv * o.w);
}

// ---------------- final layer: float4 gather + finalize only (dim 4, 1 lane/node) ----------------
__global__ __launch_bounds__(256) void k_final(
    const int* __restrict__ ell,
    const float* __restrict__ dinv, const float* __restrict__ bias,
    const float* __restrict__ Tin, float* __restrict__ Tout, int N)
{
    int n = blockIdx.x * 256 + threadIdx.x;
    if (n >= N) return;
    const int* __restrict__ row = ell + (size_t)n * ELLW;
    int dg = min(row[0], ELLW - 4);
    float dv = dinv[n];
    const float4* __restrict__ T4 = (const float4*)Tin;

    float4 a0 = T4[n];
    float4 a1 = make_float4(0.f, 0.f, 0.f, 0.f);
    float4 a2 = a1, a3 = a1;
    const int4* __restrict__ rowv = (const int4*)(row + 4);
    int k = 0;
    for (; k + 3 < dg; k += 4) {
        int4 s4 = rowv[k >> 2];
        float4 v0 = T4[s4.x], v1 = T4[s4.y], v2 = T4[s4.z], v3 = T4[s4.w];
        a0.x += v0.x; a0.y += v0.y; a0.z += v0.z; a0.w += v0.w;
        a1.x += v1.x; a1.y += v1.y; a1.z += v1.z; a1.w += v1.w;
        a2.x += v2.x; a2.y += v2.y; a2.z += v2.z; a2.w += v2.w;
        a3.x += v3.x; a3.y += v3.y; a3.z += v3.z; a3.w += v3.w;
    }
    for (; k < dg; ++k) {
        float4 v = T4[row[4 + k]];
        a0.x += v.x; a0.y += v.y; a0.z += v.z; a0.w += v.w;
    }
    float4 b = *(const float4*)bias;
    ((float4*)Tout)[n] = make_float4(
        fmaxf(dv * (a0.x + a1.x + a2.x + a3.x) + b.x, 0.0f),
        fmaxf(dv * (a0.y + a1.y + a2.y + a3.y) + b.y, 0.0f),
        fmaxf(dv * (a0.z + a1.z + a2.z + a3.z) + b.z, 0.0f),
        fmaxf(dv * (a0.w + a1.w + a2.w + a3.w) + b.w, 0.0f));
}

// ---------------- FC: [1000,1200] @ [1200,4] + bias ----------------
__global__ __launch_bounds__(256) void k_fc(
    const float* __restrict__ H, const float* __restrict__ Wfc,
    const float* __restrict__ bfc, float* __restrict__ out)
{
    int r = blockIdx.x;          // 1000 rows
    int t = threadIdx.x;
    float p0 = 0.f, p1 = 0.f, p2 = 0.f, p3 = 0.f;
    for (int k = t; k < 1200; k += 256) {
        float h = H[(size_t)r * 1200 + k];
        p0 += h * Wfc[k * 4 + 0];
        p1 += h * Wfc[k * 4 + 1];
        p2 += h * Wfc[k * 4 + 2];
        p3 += h * Wfc[k * 4 + 3];
    }
#pragma unroll
    for (int off = 32; off > 0; off >>= 1) {
        p0 += __shfl_down(p0, off);
        p1 += __shfl_down(p1, off);
        p2 += __shfl_down(p2, off);
        p3 += __shfl_down(p3, off);
    }
    __shared__ float red[4][4];
    int w = t >> 6, lane = t & 63;
    if (lane == 0) { red[w][0] = p0; red[w][1] = p1; red[w][2] = p2; red[w][3] = p3; }
    __syncthreads();
    if (t < 4) {
        float s = red[0][t] + red[1][t] + red[2][t] + red[3][t];
        out[r * 4 + t] = s + bfc[t];
    }
}

// ---------------------------------------------------------------------------
extern "C" void kernel_launch(void* const* d_in, const int* in_sizes, int n_in,
                              void* d_out, int out_size, void* d_ws, size_t ws_size,
                              hipStream_t stream) {
    const float* x   = (const float*)d_in[0];
    const int*   ei  = (const int*)d_in[1];
    const float* W1  = (const float*)d_in[2];
    const float* b1  = (const float*)d_in[3];
    const float* g1  = (const float*)d_in[4];
    const float* be1 = (const float*)d_in[5];
    const float* m1  = (const float*)d_in[6];
    const float* v1  = (const float*)d_in[7];
    const float* W2  = (const float*)d_in[8];
    const float* b2  = (const float*)d_in[9];
    const float* g2  = (const float*)d_in[10];
    const float* be2 = (const float*)d_in[11];
    const float* m2  = (const float*)d_in[12];
    const float* v2  = (const float*)d_in[13];
    const float* Wc1 = (const float*)d_in[14];
    const float* bc1 = (const float*)d_in[15];
    const float* Wc2 = (const float*)d_in[16];
    const float* bc2 = (const float*)d_in[17];
    const float* Wc3 = (const float*)d_in[18];
    const float* bc3 = (const float*)d_in[19];
    const float* Wc4 = (const float*)d_in[20];
    const float* bc4 = (const float*)d_in[21];
    const float* Wc5 = (const float*)d_in[22];
    const float* bc5 = (const float*)d_in[23];
    const float* Wfc = (const float*)d_in[24];
    const float* bfc = (const float*)d_in[25];

    const int N = in_sizes[0] / 25;          // 300000
    const int E = in_sizes[1] / 2;           // 3000000
    const int NBUCK = (N + NPB - 1) >> BSH2; // 147

    // ---- workspace layout (256B aligned) ----
    char* ws = (char*)d_ws;
    size_t off = 0;
    auto alloc = [&](size_t bytes) { size_t o = off; off += (bytes + 255) & ~(size_t)255; return o; };
    size_t o_flag = alloc(256);
    size_t o_gcnt = alloc((size_t)MAXBK * 4);
    size_t o_dinv = alloc((size_t)N * 4);
    size_t o_ell  = alloc((size_t)N * ELLW * 4);   // 57.6 MB
    size_t o_A = alloc((size_t)N * 32 * 4);        // stride-32 buffer (38.4 MB)
    size_t o_B = alloc((size_t)N * 16 * 4);        // stride-16 buffer (19.2 MB)
    (void)alloc(4096);                             // tail pad

    int*   flag = (int*)(ws + o_flag);
    int*   gcnt = (int*)(ws + o_gcnt);
    float* dinv = (float*)(ws + o_dinv);
    int*   ell  = (int*)(ws + o_ell);
    float* A = (float*)(ws + o_A);
    float* B_ = (float*)(ws + o_B);
    int*   bdata = (int*)A;   // 15.7 MB alias: dead before k_ffn writes A (stream-ordered)

    const int B = 256;
    int gN = (N + B - 1) / B;
    int gP = (E + 1023) / 1024;

    k_detect<<<1, 64, 0, stream>>>((const unsigned int*)ei, flag);
    hipMemsetAsync(gcnt, 0, (size_t)MAXBK * 4, stream);
    k_part<<<gP, B, 0, stream>>>(ei, flag, gcnt, bdata, E);
    k_ell2<<<NBUCK, B, 0, stream>>>(gcnt, bdata, ell, dinv, N);

    // FFN (BN folded) + layer1 dense:  T1 = A (dim 25, stride 32)
    k_ffn<<<gN, B, 0, stream>>>(x, W1, b1, g1, be1, m1, v1, W2, b2, g2, be2, m2, v2,
                                Wc1, dinv, A, N);
    // L1: gather(25,s32) + bc1 + Wc2 -> B (dim 16)
    k_layer<25, 32, 16, 8><<<(N * 8 + B - 1) / B, B, 0, stream>>>(ell, dinv, bc1, Wc2, A, B_, N);
    // L2: gather(16) + bc2 + Wc3 -> A (dim 16)
    k_layer<16, 16, 16, 4><<<(N * 4 + B - 1) / B, B, 0, stream>>>(ell, dinv, bc2, Wc3, B_, A, N);
    // L3: gather(16) + bc3 + Wc4 -> B (dim 8)
    k_layer<16, 16, 8, 4><<<(N * 4 + B - 1) / B, B, 0, stream>>>(ell, dinv, bc3, Wc4, A, B_, N);
    // L4: gather(8) + bc4 + Wc5 -> A (dim 4)
    k_layer<8, 8, 4, 2><<<(N * 2 + B - 1) / B, B, 0, stream>>>(ell, dinv, bc4, Wc5, B_, A, N);
    // L5: gather(4) + bc5 + relu -> B (dim 4, final node features)
    k_final<<<gN, B, 0, stream>>>(ell, dinv, bc5, A, B_, N);
    // FC
    k_fc<<<1000, B, 0, stream>>>(B_, Wfc, bfc, (float*)d_out);
}

// Round 9
// 505.068 us; speedup vs baseline: 1.5572x; 1.0340x over previous
//
#include <hip/hip_runtime.h>

#define BN_EPS 1e-5f
#define ELLW 48      // slot 0 = count, slots 4..47 = neighbor ids (16B-aligned), cap 44 >> max deg ~33
#define BSH2 11      // bucket = dst >> 11  (2048 nodes per bucket)
#define NPB 2048
#define MAXBK 160    // compile-time bound on bucket count (N <= 327680)
#define BCAP2 26624  // per-bucket edge capacity (mean ~20.4K, +43 sigma)

// ---------------- detect int64 vs int32 edge_index ----------------
__global__ void k_detect(const unsigned int* __restrict__ ei, int* __restrict__ flag) {
    int t = threadIdx.x;                 // 64 threads, one wave
    unsigned int v = ei[2 * t + 1];      // odd words: int64 high-halves (==0) or real int32 values
    unsigned long long mask = __ballot(v != 0);
    if (t == 0) flag[0] = (mask == 0ULL) ? 1 : 0;   // 1 => int64
}

// ---------------- pass 1: block-grouped partition by dst>>11 ----------------
__global__ __launch_bounds__(256) void k_part(
    const int* __restrict__ ei, const int* __restrict__ flag,
    int* __restrict__ gcnt, int* __restrict__ bdata, int E)
{
    __shared__ int hist[MAXBK];
    __shared__ int cur[MAXBK];
    __shared__ int gbase[MAXBK];
    __shared__ int locstart[MAXBK + 1];
    __shared__ int sc[256];
    __shared__ int stage[1024];

    int t = threadIdx.x;
    int blockBase = blockIdx.x * 1024;
    int blockCnt = E - blockBase; if (blockCnt > 1024) blockCnt = 1024; if (blockCnt < 0) blockCnt = 0;

    for (int i = t; i < MAXBK; i += 256) hist[i] = 0;
    __syncthreads();

    bool w64 = (flag[0] != 0);
    int e = blockBase + t * 4;
    int s[4], d[4];
    int cnt = 0;
    if (e < E) {
        cnt = E - e; if (cnt > 4) cnt = 4;
        if (cnt == 4) {
            if (w64) {
                const int4* ps = (const int4*)(ei + (size_t)2 * e);
                int4 a = ps[0], b = ps[1];
                s[0] = a.x; s[1] = a.z; s[2] = b.x; s[3] = b.z;
                const int4* pd = (const int4*)(ei + (size_t)2 * ((size_t)E + e));
                int4 c = pd[0], f = pd[1];
                d[0] = c.x; d[1] = c.z; d[2] = f.x; d[3] = f.z;
            } else {
                int4 a = *(const int4*)(ei + e);
                s[0] = a.x; s[1] = a.y; s[2] = a.z; s[3] = a.w;
                int4 c = *(const int4*)(ei + (size_t)E + e);
                d[0] = c.x; d[1] = c.y; d[2] = c.z; d[3] = c.w;
            }
        } else {
            for (int i = 0; i < cnt; ++i) {
                if (w64) { s[i] = ei[(size_t)2 * (e + i)]; d[i] = ei[(size_t)2 * ((size_t)E + e + i)]; }
                else     { s[i] = ei[e + i];               d[i] = ei[(size_t)E + e + i]; }
            }
        }
    }
    int bk[4], pk[4];
    for (int i = 0; i < cnt; ++i) {
        bk[i] = d[i] >> BSH2;
        pk[i] = (s[i] << BSH2) | (d[i] & (NPB - 1));
        atomicAdd(&hist[bk[i]], 1);
    }
    __syncthreads();

    // inclusive scan over MAXBK (padded to 256)
    sc[t] = (t < MAXBK) ? hist[t] : 0;
    __syncthreads();
    for (int off = 1; off < 256; off <<= 1) {
        int x = (t >= off) ? sc[t - off] : 0;
        __syncthreads();
        sc[t] += x;
        __syncthreads();
    }
    if (t < MAXBK) {
        locstart[t] = sc[t] - hist[t];
        cur[t] = sc[t] - hist[t];
        if (hist[t] > 0) gbase[t] = atomicAdd(&gcnt[t], hist[t]);
    }
    if (t == 255) locstart[MAXBK] = sc[MAXBK - 1];
    __syncthreads();

    // stage grouped by bucket
    for (int i = 0; i < cnt; ++i) {
        int p = atomicAdd(&cur[bk[i]], 1);
        stage[p] = pk[i];
    }
    __syncthreads();

    // copy groups out contiguously
    for (int sIdx = t; sIdx < blockCnt; sIdx += 256) {
        int lo = 0, hi = MAXBK;
        while (hi - lo > 1) {
            int mid = (lo + hi) >> 1;
            if (locstart[mid] <= sIdx) lo = mid; else hi = mid;
        }
        int g = gbase[lo] + (sIdx - locstart[lo]);
        if (g < BCAP2) bdata[(size_t)lo * BCAP2 + g] = stage[sIdx];
    }
}

// ---------------- pass 2: one block per bucket; LDS slot alloc; write ELL + count + dinv ----------------
__global__ __launch_bounds__(256) void k_ell2(
    const int* __restrict__ gcnt, const int* __restrict__ bdata,
    int* __restrict__ ell, float* __restrict__ dinv, int N)
{
    __shared__ int lcnt[NPB];
    int b = blockIdx.x;
    int t = threadIdx.x;
    for (int i = t; i < NPB; i += 256) lcnt[i] = 0;
    __syncthreads();
    int base = b << BSH2;
    int cnt = min(gcnt[b], BCAP2);
    const int* __restrict__ bd = bdata + (size_t)b * BCAP2;
    for (int i = t; i < cnt; i += 256) {
        int v = bd[i];
        int dl = v & (NPB - 1);
        int src = v >> BSH2;                      // v < 2^30, arithmetic shift fine
        int pos = atomicAdd(&lcnt[dl], 1);
        if (pos < ELLW - 4)
            ell[(size_t)(base + dl) * ELLW + 4 + pos] = src;
    }
    __syncthreads();
    for (int i = t; i < NPB; i += 256) {
        int n = base + i;
        if (n < N) {
            int c = lcnt[i];
            ell[(size_t)n * ELLW] = c;
            dinv[n] = 1.0f / sqrtf((float)(c + 1));   // +1 self-loop
        }
    }
}

// ---------------- fused FFN (BN-folded) + GCN layer-1 dense; out stride 32 ----------------
// 4 lanes per node: lane l owns hidden chunk l*25..l*25+24 (stage 1+2 partial),
// __shfl_xor group reduction, then output slice l*8..l*8+7 (stage 3).
__global__ __launch_bounds__(256) void k_ffn(
    const float* __restrict__ x,
    const float* __restrict__ W1, const float* __restrict__ b1,
    const float* __restrict__ g1, const float* __restrict__ be1,
    const float* __restrict__ m1, const float* __restrict__ v1,
    const float* __restrict__ W2, const float* __restrict__ b2,
    const float* __restrict__ g2, const float* __restrict__ be2,
    const float* __restrict__ m2, const float* __restrict__ v2,
    const float* __restrict__ Wc1,
    const float* __restrict__ dinv,
    float* __restrict__ T, int N)
{
    __shared__ float sW1c[4 * 25 * 28];   // [kc][j][k'] padded rows of 28
    __shared__ float sW2p[100 * 28];      // [k][j2]     padded rows of 28
    __shared__ float sWcp[25 * 32];       // [k][j]      stride 32, cols 25..31 zero
    __shared__ float sB1[100], sS1[100];
    __shared__ float sB2[32], sS2[32];
    int t = threadIdx.x;
    if (t < 100) {
        float s = g1[t] * rsqrtf(v1[t] + BN_EPS);
        sS1[t] = s;
        sB1[t] = (b1[t] - m1[t]) * s + be1[t];
    }
    if (t >= 128 && t < 153) {
        int u = t - 128;
        float s = g2[u] * rsqrtf(v2[u] + BN_EPS);
        sS2[u] = s;
        sB2[u] = (b2[u] - m2[u]) * s + be2[u];
    }
    __syncthreads();
    for (int q = t; q < 2500; q += 256) {
        int j = q / 100, k = q % 100;
        int kc = k / 25, kk = k % 25;
        sW1c[(kc * 25 + j) * 28 + kk] = W1[q] * sS1[k];
    }
    for (int q = t; q < 2500; q += 256) {
        int k = q / 25, j2 = q % 25;
        sW2p[k * 28 + j2] = W2[q] * sS2[j2];
    }
    for (int q = t; q < 800; q += 256) {
        int k = q >> 5, j = q & 31;
        sWcp[q] = (j < 25) ? Wc1[k * 25 + j] : 0.0f;
    }
    __syncthreads();

    int g = t >> 2;        // node within block (0..63)
    int l = t & 3;         // lane role within node
    int n = blockIdx.x * 64 + g;
    if (n >= N) return;

    float xi[25];
#pragma unroll
    for (int j = 0; j < 25; ++j) xi[j] = x[(size_t)n * 25 + j];

    // stage 1: hidden chunk l*25..l*25+24
    float hm[25];
#pragma unroll
    for (int kk = 0; kk < 25; ++kk) hm[kk] = sB1[l * 25 + kk];
#pragma unroll
    for (int j = 0; j < 25; ++j) {
        float xv = xi[j];
        const float* __restrict__ wr = &sW1c[(l * 25 + j) * 28];
#pragma unroll
        for (int kk = 0; kk < 25; ++kk) hm[kk] += xv * wr[kk];
    }

    // stage 2: partial h0 from own 25 hidden units
    float h0[25];
#pragma unroll
    for (int j2 = 0; j2 < 25; ++j2) h0[j2] = 0.0f;
#pragma unroll
    for (int kk = 0; kk < 25; ++kk) {
        float r = fmaxf(hm[kk], 0.0f);
        const float* __restrict__ w2r = &sW2p[(l * 25 + kk) * 28];
#pragma unroll
        for (int j2 = 0; j2 < 25; ++j2) h0[j2] += r * w2r[j2];
    }
    // reduce partials across the 4-lane group; bias after reduction
#pragma unroll
    for (int j2 = 0; j2 < 25; ++j2) {
        h0[j2] += __shfl_xor(h0[j2], 1);
        h0[j2] += __shfl_xor(h0[j2], 2);
        h0[j2] += sB2[j2];
    }

    // stage 3: output slice l*8..l*8+7 (cols >=25 are zero via padded weights)
    float dv = dinv[n];
    float o[8];
#pragma unroll
    for (int jj = 0; jj < 8; ++jj) o[jj] = 0.0f;
#pragma unroll
    for (int k = 0; k < 25; ++k) {
        float hv = h0[k];
        const float* __restrict__ wr = &sWcp[k * 32 + l * 8];
#pragma unroll
        for (int jj = 0; jj < 8; ++jj) o[jj] += hv * wr[jj];
    }
    float4* T4 = (float4*)(T + (size_t)n * 32 + l * 8);
    T4[0] = make_float4(dv * o[0], dv * o[1], dv * o[2], dv * o[3]);
    T4[1] = make_float4(dv * o[4], dv * o[5], dv * o[6], dv * o[7]);
}

// ---------------- fused layer: float4 gather (ELL) + finalize + dense + scale ----------------
// LPN = lanes/node, each lane owns 4 features. SI = input stride (floats, mult of 4).
template <int DI, int SI, int DO, int LPN>
__global__ __launch_bounds__(256) void k_layer(
    const int* __restrict__ ell,
    const float* __restrict__ dinv, const float* __restrict__ bias,   // bias: [DI]
    const float* __restrict__ W,                                      // [DI x DO]
    const float* __restrict__ Tin, float* __restrict__ Tout, int N)
{
    constexpr int SI4 = SI / 4;
    constexpr int DO4 = DO / 4;
    constexpr int PAD = LPN * 4;
    __shared__ float sW[DI * DO];
    __shared__ float sB[PAD];
    int t = threadIdx.x;
    for (int i = t; i < DI * DO; i += 256) sW[i] = W[i];
    for (int i = t; i < PAD; i += 256) sB[i] = (i < DI) ? bias[i] : 0.0f;
    __syncthreads();

    int g = t / LPN;
    int j = t % LPN;
    int n = blockIdx.x * (256 / LPN) + g;
    int nc = (n < N) ? n : (N - 1);
    const int* __restrict__ row = ell + (size_t)nc * ELLW;
    int dg = min(row[0], ELLW - 4);
    if (n >= N) dg = 0;
    float dv = dinv[nc];
    const float4* __restrict__ T4 = (const float4*)Tin;

    float4 a0 = T4[(size_t)nc * SI4 + j];   // self-loop term
    float4 a1 = make_float4(0.f, 0.f, 0.f, 0.f);
    float4 a2 = a1, a3 = a1;
    const int4* __restrict__ rowv = (const int4*)(row + 4);
    int k = 0;
    for (; k + 3 < dg; k += 4) {
        int4 s4 = rowv[k >> 2];
        float4 v0 = T4[(size_t)s4.x * SI4 + j];
        float4 v1 = T4[(size_t)s4.y * SI4 + j];
        float4 v2 = T4[(size_t)s4.z * SI4 + j];
        float4 v3 = T4[(size_t)s4.w * SI4 + j];
        a0.x += v0.x; a0.y += v0.y; a0.z += v0.z; a0.w += v0.w;
        a1.x += v1.x; a1.y += v1.y; a1.z += v1.z; a1.w += v1.w;
        a2.x += v2.x; a2.y += v2.y; a2.z += v2.z; a2.w += v2.w;
        a3.x += v3.x; a3.y += v3.y; a3.z += v3.z; a3.w += v3.w;
    }
    for (; k < dg; ++k) {
        float4 v = T4[(size_t)row[4 + k] * SI4 + j];
        a0.x += v.x; a0.y += v.y; a0.z += v.z; a0.w += v.w;
    }
    float ar[4];
    ar[0] = fmaxf(dv * (a0.x + a1.x + a2.x + a3.x) + sB[4 * j + 0], 0.0f);
    ar[1] = fmaxf(dv * (a0.y + a1.y + a2.y + a3.y) + sB[4 * j + 1], 0.0f);
    ar[2] = fmaxf(dv * (a0.z + a1.z + a2.z + a3.z) + sB[4 * j + 2], 0.0f);
    ar[3] = fmaxf(dv * (a0.w + a1.w + a2.w + a3.w) + sB[4 * j + 3], 0.0f);

    // dense via intra-group shuffle all-to-all (k-th activation = comp k&3 of lane base+(k>>2))
    int lane = t & 63;
    int base = lane - j;
    int jo = (j < DO4) ? j : 0;
    const float4* __restrict__ sW4 = (const float4*)sW;
    float4 o = make_float4(0.f, 0.f, 0.f, 0.f);
#pragma unroll
    for (int k2 = 0; k2 < DI; ++k2) {
        float av = __shfl(ar[k2 & 3], base + (k2 >> 2));
        float4 w = sW4[k2 * DO4 + jo];
        o.x += av * w.x; o.y += av * w.y; o.z += av * w.z; o.w += av * w.w;
    }
    if (n < N && j < DO4)
        ((float4*)Tout)[(size_t)n * DO4 + j] =
            make_float4(dv * o.x, dv * o.y, dv * o.z, dv * o.w);
}

// ---------------- final layer: float4 gather + finalize only (dim 4, 1 lane/node) ----------------
__global__ __launch_bounds__(256) void k_final(
    const int* __restrict__ ell,
    const float* __restrict__ dinv, const float* __restrict__ bias,
    const float* __restrict__ Tin, float* __restrict__ Tout, int N)
{
    int n = blockIdx.x * 256 + threadIdx.x;
    if (n >= N) return;
    const int* __restrict__ row = ell + (size_t)n * ELLW;
    int dg = min(row[0], ELLW - 4);
    float dv = dinv[n];
    const float4* __restrict__ T4 = (const float4*)Tin;

    float4 a0 = T4[n];
    float4 a1 = make_float4(0.f, 0.f, 0.f, 0.f);
    float4 a2 = a1, a3 = a1;
    const int4* __restrict__ rowv = (const int4*)(row + 4);
    int k = 0;
    for (; k + 3 < dg; k += 4) {
        int4 s4 = rowv[k >> 2];
        float4 v0 = T4[s4.x], v1 = T4[s4.y], v2 = T4[s4.z], v3 = T4[s4.w];
        a0.x += v0.x; a0.y += v0.y; a0.z += v0.z; a0.w += v0.w;
        a1.x += v1.x; a1.y += v1.y; a1.z += v1.z; a1.w += v1.w;
        a2.x += v2.x; a2.y += v2.y; a2.z += v2.z; a2.w += v2.w;
        a3.x += v3.x; a3.y += v3.y; a3.z += v3.z; a3.w += v3.w;
    }
    for (; k < dg; ++k) {
        float4 v = T4[row[4 + k]];
        a0.x += v.x; a0.y += v.y; a0.z += v.z; a0.w += v.w;
    }
    float4 b = *(const float4*)bias;
    ((float4*)Tout)[n] = make_float4(
        fmaxf(dv * (a0.x + a1.x + a2.x + a3.x) + b.x, 0.0f),
        fmaxf(dv * (a0.y + a1.y + a2.y + a3.y) + b.y, 0.0f),
        fmaxf(dv * (a0.z + a1.z + a2.z + a3.z) + b.z, 0.0f),
        fmaxf(dv * (a0.w + a1.w + a2.w + a3.w) + b.w, 0.0f));
}

// ---------------- FC: [1000,1200] @ [1200,4] + bias ----------------
__global__ __launch_bounds__(256) void k_fc(
    const float* __restrict__ H, const float* __restrict__ Wfc,
    const float* __restrict__ bfc, float* __restrict__ out)
{
    int r = blockIdx.x;          // 1000 rows
    int t = threadIdx.x;
    float p0 = 0.f, p1 = 0.f, p2 = 0.f, p3 = 0.f;
    for (int k = t; k < 1200; k += 256) {
        float h = H[(size_t)r * 1200 + k];
        p0 += h * Wfc[k * 4 + 0];
        p1 += h * Wfc[k * 4 + 1];
        p2 += h * Wfc[k * 4 + 2];
        p3 += h * Wfc[k * 4 + 3];
    }
#pragma unroll
    for (int off = 32; off > 0; off >>= 1) {
        p0 += __shfl_down(p0, off);
        p1 += __shfl_down(p1, off);
        p2 += __shfl_down(p2, off);
        p3 += __shfl_down(p3, off);
    }
    __shared__ float red[4][4];
    int w = t >> 6, lane = t & 63;
    if (lane == 0) { red[w][0] = p0; red[w][1] = p1; red[w][2] = p2; red[w][3] = p3; }
    __syncthreads();
    if (t < 4) {
        float s = red[0][t] + red[1][t] + red[2][t] + red[3][t];
        out[r * 4 + t] = s + bfc[t];
    }
}

// ---------------------------------------------------------------------------
extern "C" void kernel_launch(void* const* d_in, const int* in_sizes, int n_in,
                              void* d_out, int out_size, void* d_ws, size_t ws_size,
                              hipStream_t stream) {
    const float* x   = (const float*)d_in[0];
    const int*   ei  = (const int*)d_in[1];
    const float* W1  = (const float*)d_in[2];
    const float* b1  = (const float*)d_in[3];
    const float* g1  = (const float*)d_in[4];
    const float* be1 = (const float*)d_in[5];
    const float* m1  = (const float*)d_in[6];
    const float* v1  = (const float*)d_in[7];
    const float* W2  = (const float*)d_in[8];
    const float* b2  = (const float*)d_in[9];
    const float* g2  = (const float*)d_in[10];
    const float* be2 = (const float*)d_in[11];
    const float* m2  = (const float*)d_in[12];
    const float* v2  = (const float*)d_in[13];
    const float* Wc1 = (const float*)d_in[14];
    const float* bc1 = (const float*)d_in[15];
    const float* Wc2 = (const float*)d_in[16];
    const float* bc2 = (const float*)d_in[17];
    const float* Wc3 = (const float*)d_in[18];
    const float* bc3 = (const float*)d_in[19];
    const float* Wc4 = (const float*)d_in[20];
    const float* bc4 = (const float*)d_in[21];
    const float* Wc5 = (const float*)d_in[22];
    const float* bc5 = (const float*)d_in[23];
    const float* Wfc = (const float*)d_in[24];
    const float* bfc = (const float*)d_in[25];

    const int N = in_sizes[0] / 25;          // 300000
    const int E = in_sizes[1] / 2;           // 3000000
    const int NBUCK = (N + NPB - 1) >> BSH2; // 147

    // ---- workspace layout (256B aligned) ----
    char* ws = (char*)d_ws;
    size_t off = 0;
    auto alloc = [&](size_t bytes) { size_t o = off; off += (bytes + 255) & ~(size_t)255; return o; };
    size_t o_flag = alloc(256);
    size_t o_gcnt = alloc((size_t)MAXBK * 4);
    size_t o_dinv = alloc((size_t)N * 4);
    size_t o_ell  = alloc((size_t)N * ELLW * 4);   // 57.6 MB
    size_t o_A = alloc((size_t)N * 32 * 4);        // stride-32 buffer (38.4 MB)
    size_t o_B = alloc((size_t)N * 16 * 4);        // stride-16 buffer (19.2 MB)
    (void)alloc(4096);                             // tail pad

    int*   flag = (int*)(ws + o_flag);
    int*   gcnt = (int*)(ws + o_gcnt);
    float* dinv = (float*)(ws + o_dinv);
    int*   ell  = (int*)(ws + o_ell);
    float* A = (float*)(ws + o_A);
    float* B_ = (float*)(ws + o_B);
    int*   bdata = (int*)A;   // 15.7 MB alias: dead before k_ffn writes A (stream-ordered)

    const int B = 256;
    int gN = (N + B - 1) / B;
    int gF = (N + 63) / 64;
    int gP = (E + 1023) / 1024;

    k_detect<<<1, 64, 0, stream>>>((const unsigned int*)ei, flag);
    hipMemsetAsync(gcnt, 0, (size_t)MAXBK * 4, stream);
    k_part<<<gP, B, 0, stream>>>(ei, flag, gcnt, bdata, E);
    k_ell2<<<NBUCK, B, 0, stream>>>(gcnt, bdata, ell, dinv, N);

    // FFN (BN folded) + layer1 dense:  T1 = A (dim 25, stride 32)
    k_ffn<<<gF, B, 0, stream>>>(x, W1, b1, g1, be1, m1, v1, W2, b2, g2, be2, m2, v2,
                                Wc1, dinv, A, N);
    // L1: gather(25,s32) + bc1 + Wc2 -> B (dim 16)
    k_layer<25, 32, 16, 8><<<(N * 8 + B - 1) / B, B, 0, stream>>>(ell, dinv, bc1, Wc2, A, B_, N);
    // L2: gather(16) + bc2 + Wc3 -> A (dim 16)
    k_layer<16, 16, 16, 4><<<(N * 4 + B - 1) / B, B, 0, stream>>>(ell, dinv, bc2, Wc3, B_, A, N);
    // L3: gather(16) + bc3 + Wc4 -> B (dim 8)
    k_layer<16, 16, 8, 4><<<(N * 4 + B - 1) / B, B, 0, stream>>>(ell, dinv, bc3, Wc4, A, B_, N);
    // L4: gather(8) + bc4 + Wc5 -> A (dim 4)
    k_layer<8, 8, 4, 2><<<(N * 2 + B - 1) / B, B, 0, stream>>>(ell, dinv, bc4, Wc5, B_, A, N);
    // L5: gather(4) + bc5 + relu -> B (dim 4, final node features)
    k_final<<<gN, B, 0, stream>>>(ell, dinv, bc5, A, B_, N);
    // FC
    k_fc<<<1000, B, 0, stream>>>(B_, Wfc, bfc, (float*)d_out);
}